// Round 7
// baseline (6896.751 us; speedup 1.0000x reference)
//
#include <hip/hip_runtime.h>

#define T_STEPS 32
#define BATCH   16
#define NTHR    1024
#define NWAVE   16
#define NIN     192
#define CO      332

__device__ __forceinline__ float waveSum(float v) {
#pragma unroll
  for (int off = 32; off > 0; off >>= 1) v += __shfl_xor(v, off, 64);
  return v;
}
__device__ __forceinline__ float sigmoidf(float x) { return 1.f / (1.f + __expf(-x)); }
__device__ __forceinline__ float softplusf(float x) { return x > 15.f ? x : log1pf(__expf(x)); }

// One block per batch element; memory matrix lives in per-thread VGPRs:
// thread tid owns rows l = 4*tid + j (j=0..3), m[j][w] = mem[l][w].
// Zero cross-block communication -> plain launch, __syncthreads only.
__global__ void __launch_bounds__(NTHR, 1) ntm_kernel(
    const float* __restrict__ inp, const float* __restrict__ Wc,
    const float* __restrict__ bcv, float* __restrict__ dout)
{
  const int b    = blockIdx.x;
  const int tid  = threadIdx.x;
  const int wv   = tid >> 6;
  const int lane = tid & 63;

  __shared__ __align__(16) float kr[64], kw[64], elds[64], alds[64];
  __shared__ __align__(16) float rscr[NWAVE][64];   // read-vector wave partials
  __shared__ float xin[NIN], psc[12];
  __shared__ float outb[2][64], rsum[64];
  __shared__ float scrA[NWAVE], scrB[NWAVE], red[6];
  __shared__ float eRj3[16], eRj0[16], eWj3[16], eWj0[16];  // er wave-edges
  __shared__ float pRj3[16], pRj0[16], pWj3[16], pWj0[16];  // wp wave-edges

  // register-resident memory rows
  float m[4][64];
#pragma unroll
  for (int j = 0; j < 4; ++j)
#pragma unroll
    for (int w = 0; w < 64; ++w) m[j][w] = 0.f;

  float wpR[4] = {0.f, 0.f, 0.f, 0.f}, wpW[4] = {0.f, 0.f, 0.f, 0.f};
  if (tid == 0) { wpR[0] = 1.f; wpW[0] = 1.f; }     // w0 one-hot at l=0
  if (tid < 64) { rsum[tid] = 0.f; outb[0][tid] = 0.f; outb[1][tid] = 0.f; }
  if (lane == 63) { pRj3[wv] = 0.f; pWj3[wv] = 0.f; }
  if (lane == 0)  { float v0 = (tid == 0) ? 1.f : 0.f; pRj0[wv] = v0; pWj0[wv] = v0; }
  __syncthreads();

  for (int t = 0; t < T_STEPS; ++t) {
    // ---------------- stage controller input ----------------
    if (tid < 64)       xin[tid] = inp[((size_t)t * BATCH + b) * 64 + tid];
    else if (tid < 128) xin[tid] = outb[(t + 1) & 1][tid - 64];
    else if (tid < 192) xin[tid] = rsum[tid - 128];
    __syncthreads();

    // ---------------- controller GEMM: 2 threads per column ----------------
    if (tid < 2 * CO) {
      const int col = tid >> 1, h = tid & 1;
      float acc = h ? 0.f : bcv[col];
      const float* wcp = Wc + col + (size_t)(96 * h) * CO;
#pragma unroll 8
      for (int i = 0; i < 96; ++i) acc = fmaf(xin[96 * h + i], wcp[(size_t)i * CO], acc);
      acc += __shfl_xor(acc, 1, 64);
      if (h == 0) {
        if (col < 64) {
          outb[t & 1][col] = acc;
          dout[((size_t)t * BATCH + b) * 64 + col] = acc;
        }
        else if (col < 128) kr[col - 64] = acc;
        else if (col < 134) psc[col - 128] = acc;        // beta_r,g_r,ga_r,s_r0..2
        else if (col < 198) kw[col - 134] = acc;
        else if (col < 204) psc[6 + (col - 198)] = acc;  // beta_w,g_w,ga_w,s_w0..2
        else if (col < 268) elds[col - 204] = sigmoidf(acc);
        else                alds[col - 268] = acc;
      }
    }
    __syncthreads();
    if (wv == 0)      { float v = kr[lane]; float s = waveSum(v * v); if (!lane) red[4] = 1.f / sqrtf(s + 1e-14f); }
    else if (wv == 1) { float v = kw[lane]; float s = waveSum(v * v); if (!lane) red[5] = 1.f / sqrtf(s + 1e-14f); }
    __syncthreads();

    // ---------------- phase A: content addressing (register mem) ----------------
    float erR[4], erW[4];
    {
      const float invnkR = red[4], invnkW = red[5];
      const float betaR = softplusf(psc[0]), betaW = softplusf(psc[6]);
      float ss[4] = {0, 0, 0, 0}, dr[4] = {0, 0, 0, 0}, dw[4] = {0, 0, 0, 0};
#pragma unroll
      for (int w4 = 0; w4 < 16; ++w4) {
        float4 r4 = ((const float4*)kr)[w4];
        float4 w4v = ((const float4*)kw)[w4];
#pragma unroll
        for (int j = 0; j < 4; ++j) {
          float v0 = m[j][4 * w4 + 0], v1 = m[j][4 * w4 + 1];
          float v2 = m[j][4 * w4 + 2], v3 = m[j][4 * w4 + 3];
          ss[j] = fmaf(v0, v0, fmaf(v1, v1, fmaf(v2, v2, fmaf(v3, v3, ss[j]))));
          dr[j] = fmaf(v0, r4.x, fmaf(v1, r4.y, fmaf(v2, r4.z, fmaf(v3, r4.w, dr[j]))));
          dw[j] = fmaf(v0, w4v.x, fmaf(v1, w4v.y, fmaf(v2, w4v.z, fmaf(v3, w4v.w, dw[j]))));
        }
      }
      float sR = 0.f, sW = 0.f;
#pragma unroll
      for (int j = 0; j < 4; ++j) {
        float rinv = rsqrtf(ss[j] + 1e-14f);
        erR[j] = __expf(betaR * (dr[j] * rinv * invnkR - 1.f));   // stable: K<=1
        erW[j] = __expf(betaW * (dw[j] * rinv * invnkW - 1.f));
        sR += erR[j]; sW += erW[j];
      }
      if (lane == 63) { eRj3[wv] = erR[3]; eWj3[wv] = erW[3]; }
      if (lane == 0)  { eRj0[wv] = erR[0]; eWj0[wv] = erW[0]; }
      sR = waveSum(sR); sW = waveSum(sW);
      if (!lane) { scrA[wv] = sR; scrB[wv] = sW; }
    }
    __syncthreads();
    if (wv == 0) { float v = (lane < 16) ? scrA[lane] : 0.f; v = waveSum(v); if (!lane) red[0] = 1.f / v; }
    if (wv == 1) { float v = (lane < 16) ? scrB[lane] : 0.f; v = waveSum(v); if (!lane) red[1] = 1.f / v; }
    __syncthreads();

    // ---------------- phase B: gate + shift + sharpen (registers + shuffles) ----------------
    {
      const float invSR = red[0], invSW = red[1];
      float gR = sigmoidf(psc[1]), gaR = softplusf(psc[2]) + 1.f;
      float x0 = psc[3], x1 = psc[4], x2 = psc[5];
      float mx = fmaxf(x0, fmaxf(x1, x2));
      float e0 = __expf(x0 - mx), e1 = __expf(x1 - mx), e2 = __expf(x2 - mx);
      float es = 1.f / (e0 + e1 + e2);
      float sr0 = e0 * es, sr1 = e1 * es, sr2 = e2 * es;
      float gW = sigmoidf(psc[7]), gaW = softplusf(psc[8]) + 1.f;
      float y0 = psc[9], y1 = psc[10], y2 = psc[11];
      float my = fmaxf(y0, fmaxf(y1, y2));
      float f0 = __expf(y0 - my), f1 = __expf(y1 - my), f2 = __expf(y2 - my);
      float fs = 1.f / (f0 + f1 + f2);
      float sw0 = f0 * fs, sw1 = f1 * fs, sw2 = f2 * fs;
      const float aR = gR * invSR, bR = 1.f - gR;
      const float aW = gW * invSW, bW = 1.f - gW;

      float eRm = __shfl_up(erR[3], 1, 64);   if (lane == 0)  eRm = eRj3[(wv + 15) & 15];
      float eRp = __shfl_down(erR[0], 1, 64); if (lane == 63) eRp = eRj0[(wv + 1) & 15];
      float eWm = __shfl_up(erW[3], 1, 64);   if (lane == 0)  eWm = eWj3[(wv + 15) & 15];
      float eWp = __shfl_down(erW[0], 1, 64); if (lane == 63) eWp = eWj0[(wv + 1) & 15];
      float pRm = __shfl_up(wpR[3], 1, 64);   if (lane == 0)  pRm = pRj3[(wv + 15) & 15];
      float pRp = __shfl_down(wpR[0], 1, 64); if (lane == 63) pRp = pRj0[(wv + 1) & 15];
      float pWm = __shfl_up(wpW[3], 1, 64);   if (lane == 0)  pWm = pWj3[(wv + 15) & 15];
      float pWp = __shfl_down(wpW[0], 1, 64); if (lane == 63) pWp = pWj0[(wv + 1) & 15];

      float wgR[6], wgW[6];
      wgR[0] = aR * eRm + bR * pRm;  wgW[0] = aW * eWm + bW * pWm;
#pragma unroll
      for (int j = 0; j < 4; ++j) {
        wgR[j + 1] = aR * erR[j] + bR * wpR[j];
        wgW[j + 1] = aW * erW[j] + bW * wpW[j];
      }
      wgR[5] = aR * eRp + bR * pRp;  wgW[5] = aW * eWp + bW * pWp;

      float wbR[4], wbW[4], pRs = 0.f, pWs = 0.f;
#pragma unroll
      for (int j = 0; j < 4; ++j) {
        wbR[j] = __powf(sr0 * wgR[j] + sr1 * wgR[j + 1] + sr2 * wgR[j + 2], gaR);
        wbW[j] = __powf(sw0 * wgW[j] + sw1 * wgW[j + 1] + sw2 * wgW[j + 2], gaW);
        pRs += wbR[j]; pWs += wbW[j];
      }
      pRs = waveSum(pRs); pWs = waveSum(pWs);
      if (!lane) { scrA[wv] = pRs; scrB[wv] = pWs; }
      __syncthreads();
      if (wv == 0) { float v = (lane < 16) ? scrA[lane] : 0.f; v = waveSum(v); if (!lane) red[2] = 1.f / v; }
      if (wv == 1) { float v = (lane < 16) ? scrB[lane] : 0.f; v = waveSum(v); if (!lane) red[3] = 1.f / v; }
      __syncthreads();
      const float invPR = red[2], invPW = red[3];
#pragma unroll
      for (int j = 0; j < 4; ++j) {
        wpR[j] = wbR[j] * invPR;   // normalized; also w_prev for t+1
        wpW[j] = wbW[j] * invPW;
      }
      if (lane == 63) { pRj3[wv] = wpR[3]; pWj3[wv] = wpW[3]; }
      if (lane == 0)  { pRj0[wv] = wpR[0]; pWj0[wv] = wpW[0]; }
    }

    // ---------------- phase C: read partials + memory update (register mem) ----------------
    float racc[64];
#pragma unroll
    for (int w = 0; w < 64; ++w) racc[w] = 0.f;
#pragma unroll
    for (int w4 = 0; w4 < 16; ++w4) {
      float4 e4 = ((const float4*)elds)[w4];
      float4 a4 = ((const float4*)alds)[w4];
#pragma unroll
      for (int j = 0; j < 4; ++j) {
        const float rw = wpR[j], ww = wpW[j];
        float v0 = m[j][4 * w4 + 0], v1 = m[j][4 * w4 + 1];
        float v2 = m[j][4 * w4 + 2], v3 = m[j][4 * w4 + 3];
        racc[4 * w4 + 0] = fmaf(v0, rw, racc[4 * w4 + 0]);
        racc[4 * w4 + 1] = fmaf(v1, rw, racc[4 * w4 + 1]);
        racc[4 * w4 + 2] = fmaf(v2, rw, racc[4 * w4 + 2]);
        racc[4 * w4 + 3] = fmaf(v3, rw, racc[4 * w4 + 3]);
        m[j][4 * w4 + 0] = fmaf(ww, a4.x, fmaf(v0, -(ww * e4.x), v0));
        m[j][4 * w4 + 1] = fmaf(ww, a4.y, fmaf(v1, -(ww * e4.y), v1));
        m[j][4 * w4 + 2] = fmaf(ww, a4.z, fmaf(v2, -(ww * e4.z), v2));
        m[j][4 * w4 + 3] = fmaf(ww, a4.w, fmaf(v3, -(ww * e4.w), v3));
      }
    }
    // reduce-scatter racc over the 64 lanes: lane L ends with partial for w=L.
    // value-select keeps all register indices static; every lane executes every shfl.
    {
      const bool u5 = (lane & 32) != 0;
      float t32[32];
#pragma unroll
      for (int j = 0; j < 32; ++j) {
        float sent = u5 ? racc[j] : racc[j + 32];
        float keep = u5 ? racc[j + 32] : racc[j];
        t32[j] = keep + __shfl_xor(sent, 32, 64);
      }
      const bool u4 = (lane & 16) != 0;
      float t16[16];
#pragma unroll
      for (int j = 0; j < 16; ++j) {
        float sent = u4 ? t32[j] : t32[j + 16];
        float keep = u4 ? t32[j + 16] : t32[j];
        t16[j] = keep + __shfl_xor(sent, 16, 64);
      }
      const bool u3 = (lane & 8) != 0;
      float t8[8];
#pragma unroll
      for (int j = 0; j < 8; ++j) {
        float sent = u3 ? t16[j] : t16[j + 8];
        float keep = u3 ? t16[j + 8] : t16[j];
        t8[j] = keep + __shfl_xor(sent, 8, 64);
      }
      const bool u2 = (lane & 4) != 0;
      float t4[4];
#pragma unroll
      for (int j = 0; j < 4; ++j) {
        float sent = u2 ? t8[j] : t8[j + 4];
        float keep = u2 ? t8[j + 4] : t8[j];
        t4[j] = keep + __shfl_xor(sent, 4, 64);
      }
      const bool u1 = (lane & 2) != 0;
      float t2[2];
#pragma unroll
      for (int j = 0; j < 2; ++j) {
        float sent = u1 ? t4[j] : t4[j + 2];
        float keep = u1 ? t4[j + 2] : t4[j];
        t2[j] = keep + __shfl_xor(sent, 2, 64);
      }
      const bool u0 = (lane & 1) != 0;
      float sent = u0 ? t2[0] : t2[1];
      float keep = u0 ? t2[1] : t2[0];
      float t1 = keep + __shfl_xor(sent, 1, 64);
      rscr[wv][lane] = t1;
    }
    __syncthreads();
    if (tid < 64) {
      float s = 0.f;
#pragma unroll
      for (int k = 0; k < NWAVE; ++k) s += rscr[k][tid];
      rsum[tid] = s;            // r(t): already normalized (wpR normalized)
    }
    __syncthreads();
  }
}

extern "C" void kernel_launch(void* const* d_in, const int* in_sizes, int n_in,
                              void* d_out, int out_size, void* d_ws, size_t ws_size,
                              hipStream_t stream) {
  const float* inp = (const float*)d_in[0];
  const float* Wc  = (const float*)d_in[1];
  const float* bcv = (const float*)d_in[2];
  float* dout = (float*)d_out;

  ntm_kernel<<<dim3(BATCH), dim3(NTHR), 0, stream>>>(inp, Wc, bcv, dout);
}

// Round 8
// 1183.082 us; speedup vs baseline: 5.8295x; 5.8295x over previous
//
#include <hip/hip_runtime.h>

#define T_STEPS 32
#define BATCH   16
#define NBPB    8
#define NBLK    (BATCH * NBPB)     // 128
#define NTHR    1024
#define LSL     512                // l-slots per block
#define MSTR    65                 // odd stride: all LDS patterns 2-way (free)
#define CO      332

// comm floats layout (zeroed by hipMemsetAsync)
#define OFF_CTR   0                                       // [16][32] uints
#define OFF_SSUM  512                                     // [b][t][4] S_R,S_W,P_R,P_W
#define OFF_RSUM  (OFF_SSUM + BATCH*T_STEPS*4)            // [b][t][64] unnormalized r~
#define OFF_HE    (OFF_RSUM + BATCH*T_STEPS*64)           // [b][t][g][4] er halos
#define OFF_HP    (OFF_HE + BATCH*T_STEPS*NBPB*4)         // [b][t=0..32][g][4] wp halos
#define OFF_OUTP  (OFF_HP + BATCH*(T_STEPS+1)*NBPB*4)     // [blk][64] out(t) private copy
#define OFF_KEA   (OFF_OUTP + NBLK*64)                    // [blk][ kr64 kw64 | ea[2][128] ]
#define COMM_FLOATS (OFF_KEA + NBLK*384)

__device__ __forceinline__ float waveSum(float v) {
#pragma unroll
  for (int off = 32; off > 0; off >>= 1) v += __shfl_xor(v, off, 64);
  return v;
}
__device__ __forceinline__ float sigmoidf(float x) { return 1.f / (1.f + __expf(-x)); }
__device__ __forceinline__ float softplusf(float x) { return x > 15.f ? x : log1pf(__expf(x)); }
__device__ __forceinline__ float aload(const float* p) {
  return __hip_atomic_load(p, __ATOMIC_RELAXED, __HIP_MEMORY_SCOPE_AGENT);
}
__device__ __forceinline__ void astore(float* p, float v) {
  __hip_atomic_store(p, v, __ATOMIC_RELAXED, __HIP_MEMORY_SCOPE_AGENT);
}

__device__ __forceinline__ void gbar(unsigned* c, unsigned expected) {
  __syncthreads();   // drains vmcnt -> all published stores/atomics visible
  if (threadIdx.x == 0) {
    atomicAdd(c, 1u);
    while (__hip_atomic_load(c, __ATOMIC_RELAXED, __HIP_MEMORY_SCOPE_AGENT) < expected)
      __builtin_amdgcn_s_sleep(1);
  }
  __syncthreads();
}

__global__ void __launch_bounds__(NTHR, 1) ntm_kernel(
    const float* __restrict__ inp, const float* __restrict__ Wc,
    const float* __restrict__ bcv, float* __restrict__ dout,
    float* __restrict__ comm)
{
  const int blkid = blockIdx.x;
  const int b   = blkid & 15;     // XCD co-location: blkid%8 == b%8
  const int g   = blkid >> 4;
  const int tid = threadIdx.x;
  const int wv  = tid >> 6;
  const int lane = tid & 63;

  __shared__ float mem[LSL * MSTR];                     // 130 KB block-private
  __shared__ float wpR[LSL], wpW[LSL];                  // normalized weights (prev)
  __shared__ float wbR[LSL], wbW[LSL];                  // sharpened, unnormalized
  __shared__ float erR[LSL], erW[LSL];                  // softmax numerators
  __shared__ float kr[64], kw[64], psc[12], paccT[CO];
  __shared__ float scrA[16], scrB[16], red[8], coef[12], edge[8];

  unsigned* ctr = (unsigned*)comm + b * 32;
  float* kea = comm + OFF_KEA + blkid * 384;
  float* outP = comm + OFF_OUTP + blkid * 64;

  // ---------------- prologue ----------------
  for (int i = tid; i < LSL * MSTR; i += NTHR) mem[i] = 0.f;
  if (tid < LSL) { wpR[tid] = 0.f; wpW[tid] = 0.f; }
  if (g == 0 && tid == 0) { wpR[0] = 1.f; wpW[0] = 1.f; }
  if (tid < CO) {            // partial(0) = bc + Wx*x(0) (out(-1)=0)
    float acc = bcv[tid];
    const float* x0 = inp + b * 64;
    const float* wc = Wc + tid;
#pragma unroll 8
    for (int i = 0; i < 64; ++i) acc = fmaf(x0[i], wc[(size_t)i * CO], acc);
    paccT[tid] = acc;
  }
  {
    float* hp0 = comm + OFF_HP + ((size_t)(b * (T_STEPS + 1)) * NBPB + g) * 4;
    if (tid == 0) { float v = (g == 0) ? 1.f : 0.f; astore(hp0 + 0, v); astore(hp0 + 2, v); }
    if (tid == 1) { astore(hp0 + 1, 0.f); astore(hp0 + 3, 0.f); }
  }
  unsigned expct = NBPB;
  gbar(ctr, expct);

  for (int t = 0; t < T_STEPS; ++t) {
    float* sS  = comm + OFF_SSUM + (size_t)(b * T_STEPS + t) * 4;
    float* rS  = comm + OFF_RSUM + (size_t)(b * T_STEPS + t) * 64;
    float* hE  = comm + OFF_HE + ((size_t)(b * T_STEPS + t) * NBPB + g) * 4;
    float* hPn = comm + OFF_HP + ((size_t)(b * (T_STEPS + 1) + t + 1) * NBPB + g) * 4;

    // ---------- phase 0: finish GEMM(t) = partial + Wr*r(t-1) ----------
    if (tid < 2 * CO) {
      const int col = tid >> 1, h = tid & 1;
      float part = h ? 0.f : paccT[col];
      if (t > 0) {
        const float* rSp = comm + OFF_RSUM + (size_t)(b * T_STEPS + t - 1) * 64;
        const float* sSp = comm + OFF_SSUM + (size_t)(b * T_STEPS + t - 1) * 4;
        const float invPR = 1.f / aload(sSp + 2);
        const float* wc = Wc + (size_t)(128 + 32 * h) * CO + col;
        float racc = 0.f;
#pragma unroll 8
        for (int j = 0; j < 32; ++j) racc = fmaf(rSp[32 * h + j], wc[(size_t)j * CO], racc);
        part = fmaf(racc, invPR, part);
      }
      float acc = part + __shfl_xor(part, 1, 64);
      if (h == 0) {
        if (col < 64) {
          if (g == 0) dout[((size_t)t * BATCH + b) * 64 + col] = acc;
          outP[col] = acc;
        } else if (col < 128)  { kr[col - 64] = acc;  kea[col - 64] = acc; }
        else if (col < 134)    psc[col - 128] = acc;
        else if (col < 198)    { kw[col - 134] = acc; kea[64 + col - 134] = acc; }
        else if (col < 204)    psc[6 + col - 198] = acc;
        else if (col < 268)    kea[128 + (t & 1) * 128 + (col - 204)] = sigmoidf(acc);
        else                   kea[128 + (t & 1) * 128 + 64 + (col - 268)] = acc;
      }
    }
    __syncthreads();
    if (wv == 0)      { float v = kr[lane]; float s = waveSum(v * v); if (!lane) red[4] = 1.f / sqrtf(s + 1e-14f); }
    else if (wv == 1) { float v = kw[lane]; float s = waveSum(v * v); if (!lane) red[5] = 1.f / sqrtf(s + 1e-14f); }
    else if (wv == 2 && !lane) { red[6] = softplusf(psc[0]); red[7] = softplusf(psc[6]); }
    __syncthreads();

    // ---------- phase 1: fused lazy-update(t-1) + content addressing ----------
    {
      const float invnkR = red[4], invnkW = red[5];
      const float betaR = red[6], betaW = red[7];
      const int l = tid >> 1, h = tid & 1;
      float* mrow = &mem[l * MSTR + 32 * h];
      float ss = 0.f, dr = 0.f, dw = 0.f;
      if (t > 0) {
        const float wWl = wpW[l];                  // normalized w_W(t-1)
        const float4* k4p = (const float4*)kea + 8 * h;          // kr half
        const float4* w4p = (const float4*)(kea + 64) + 8 * h;   // kw half
        const float4* e4p = (const float4*)(kea + 128 + ((t + 1) & 1) * 128) + 8 * h;
        const float4* a4p = (const float4*)(kea + 128 + ((t + 1) & 1) * 128 + 64) + 8 * h;
#pragma unroll
        for (int q = 0; q < 8; ++q) {
          float4 e4 = e4p[q], a4 = a4p[q], k4 = k4p[q], w4 = w4p[q];
          float v0 = mrow[4 * q + 0], v1 = mrow[4 * q + 1];
          float v2 = mrow[4 * q + 2], v3 = mrow[4 * q + 3];
          v0 = fmaf(wWl, a4.x, fmaf(v0, -(wWl * e4.x), v0));
          v1 = fmaf(wWl, a4.y, fmaf(v1, -(wWl * e4.y), v1));
          v2 = fmaf(wWl, a4.z, fmaf(v2, -(wWl * e4.z), v2));
          v3 = fmaf(wWl, a4.w, fmaf(v3, -(wWl * e4.w), v3));
          mrow[4 * q + 0] = v0; mrow[4 * q + 1] = v1;
          mrow[4 * q + 2] = v2; mrow[4 * q + 3] = v3;
          ss = fmaf(v0, v0, fmaf(v1, v1, fmaf(v2, v2, fmaf(v3, v3, ss))));
          dr = fmaf(v0, k4.x, fmaf(v1, k4.y, fmaf(v2, k4.z, fmaf(v3, k4.w, dr))));
          dw = fmaf(v0, w4.x, fmaf(v1, w4.y, fmaf(v2, w4.z, fmaf(v3, w4.w, dw))));
        }
      }
      ss += __shfl_xor(ss, 1, 64);
      dr += __shfl_xor(dr, 1, 64);
      dw += __shfl_xor(dw, 1, 64);
      float rinv = rsqrtf(ss + 1e-14f);
      float eRv = __expf(betaR * (dr * rinv * invnkR - 1.f));   // stable: K<=1
      float eWv = __expf(betaW * (dw * rinv * invnkW - 1.f));
      if (h == 0) {
        erR[l] = eRv; erW[l] = eWv;
        if (l == 0)       { astore(hE + 0, eRv); astore(hE + 2, eWv); }
        if (l == LSL - 1) { astore(hE + 1, eRv); astore(hE + 3, eWv); }
      }
      float sRl = h ? 0.f : eRv, sWl = h ? 0.f : eWv;
      sRl = waveSum(sRl); sWl = waveSum(sWl);
      if (!lane) { scrA[wv] = sRl; scrB[wv] = sWl; }
    }
    __syncthreads();
    if (tid == 0) {
      float a = 0.f, bb = 0.f;
      for (int j = 0; j < 16; ++j) { a += scrA[j]; bb += scrB[j]; }
      atomicAdd(sS + 0, a); atomicAdd(sS + 1, bb);
    }
    expct += NBPB; gbar(ctr, expct);   // barrier A

    // ---------- phase 2: sharpen + r~ partials + prefetch partial(t+1) ----------
    {
      const int gm = (g + NBPB - 1) & 7, gp = (g + 1) & 7;
      if (tid == 0) {
        float invSR = 1.f / aload(sS + 0), invSW = 1.f / aload(sS + 1);
        float gR = sigmoidf(psc[1]); coef[0] = gR * invSR; coef[1] = 1.f - gR;
        coef[2] = softplusf(psc[2]) + 1.f;
        float x0 = psc[3], x1 = psc[4], x2 = psc[5];
        float mx = fmaxf(x0, fmaxf(x1, x2));
        float e0 = __expf(x0 - mx), e1 = __expf(x1 - mx), e2 = __expf(x2 - mx);
        float es = 1.f / (e0 + e1 + e2);
        coef[3] = e0 * es; coef[4] = e1 * es; coef[5] = e2 * es;
        float gW = sigmoidf(psc[7]); coef[6] = gW * invSW; coef[7] = 1.f - gW;
        coef[8] = softplusf(psc[8]) + 1.f;
        float y0 = psc[9], y1 = psc[10], y2 = psc[11];
        float my = fmaxf(y0, fmaxf(y1, y2));
        float f0 = __expf(y0 - my), f1 = __expf(y1 - my), f2 = __expf(y2 - my);
        float fs = 1.f / (f0 + f1 + f2);
        coef[9] = f0 * fs; coef[10] = f1 * fs; coef[11] = f2 * fs;
      }
      if (tid == 1) {
        const float* hEm = comm + OFF_HE + ((size_t)(b * T_STEPS + t) * NBPB + gm) * 4;
        const float* hPm = comm + OFF_HP + ((size_t)(b * (T_STEPS + 1) + t) * NBPB + gm) * 4;
        edge[0] = aload(hEm + 1); edge[1] = aload(hEm + 3);
        edge[2] = aload(hPm + 1); edge[3] = aload(hPm + 3);
      }
      if (tid == 2) {
        const float* hEp = comm + OFF_HE + ((size_t)(b * T_STEPS + t) * NBPB + gp) * 4;
        const float* hPp = comm + OFF_HP + ((size_t)(b * (T_STEPS + 1) + t) * NBPB + gp) * 4;
        edge[4] = aload(hEp + 0); edge[5] = aload(hEp + 2);
        edge[6] = aload(hPp + 0); edge[7] = aload(hPp + 2);
      }
      __syncthreads();

      float pRl = 0.f, pWl = 0.f;
      if (tid < LSL) {
        const float aR = coef[0], bR = coef[1], gaR = coef[2];
        const float sr0 = coef[3], sr1 = coef[4], sr2 = coef[5];
        const float aW = coef[6], bW = coef[7], gaW = coef[8];
        const float sw0 = coef[9], sw1 = coef[10], sw2 = coef[11];
        float erm = tid ? erR[tid - 1] : edge[0];
        float ewm = tid ? erW[tid - 1] : edge[1];
        float prm = tid ? wpR[tid - 1] : edge[2];
        float pwm = tid ? wpW[tid - 1] : edge[3];
        float erp = (tid < LSL - 1) ? erR[tid + 1] : edge[4];
        float ewp = (tid < LSL - 1) ? erW[tid + 1] : edge[5];
        float prp = (tid < LSL - 1) ? wpR[tid + 1] : edge[6];
        float pwp = (tid < LSL - 1) ? wpW[tid + 1] : edge[7];
        float wgm = aR * erm + bR * prm;
        float wg0 = aR * erR[tid] + bR * wpR[tid];
        float wgp = aR * erp + bR * prp;
        float wR = __powf(sr0 * wgm + sr1 * wg0 + sr2 * wgp, gaR);
        float vgm = aW * ewm + bW * pwm;
        float vg0 = aW * erW[tid] + bW * wpW[tid];
        float vgp = aW * ewp + bW * pwp;
        float wW = __powf(sw0 * vgm + sw1 * vg0 + sw2 * vgp, gaW);
        wbR[tid] = wR; wbW[tid] = wW;
        pRl = wR; pWl = wW;
      }
      pRl = waveSum(pRl); pWl = waveSum(pWl);
      if (!lane && wv < 8) { scrA[wv] = pRl; scrB[wv] = pWl; }
      __syncthreads();
      if (tid == 0) {
        float a = 0.f, bb = 0.f;
        for (int j = 0; j < 8; ++j) { a += scrA[j]; bb += scrB[j]; }
        atomicAdd(sS + 2, a); atomicAdd(sS + 3, bb);
      }
      // r~ partials over post-update mem (wave wv owns rows w=4wv..4wv+3)
      float wbv[8];
#pragma unroll
      for (int k = 0; k < 8; ++k) wbv[k] = wbR[lane + 64 * k];
      float racc4[4];
#pragma unroll
      for (int r = 0; r < 4; ++r) {
        const int w = 4 * wv + r;
        float acc = 0.f;
#pragma unroll
        for (int k = 0; k < 8; ++k)
          acc = fmaf(mem[(lane + 64 * k) * MSTR + w], wbv[k], acc);
        racc4[r] = acc;
      }
      {  // 7-shuffle reduce-scatter: lane group (bit5,bit4) -> row 2*bit5+bit4
        const bool u5 = (lane & 32) != 0;
        float t2[2];
#pragma unroll
        for (int j = 0; j < 2; ++j) {
          float sent = u5 ? racc4[j] : racc4[j + 2];
          float keep = u5 ? racc4[j + 2] : racc4[j];
          t2[j] = keep + __shfl_xor(sent, 32, 64);
        }
        const bool u4 = (lane & 16) != 0;
        float sent = u4 ? t2[0] : t2[1];
        float keep = u4 ? t2[1] : t2[0];
        float t1 = keep + __shfl_xor(sent, 16, 64);
        t1 += __shfl_xor(t1, 8, 64);
        t1 += __shfl_xor(t1, 4, 64);
        t1 += __shfl_xor(t1, 2, 64);
        t1 += __shfl_xor(t1, 1, 64);
        if ((lane & 15) == 0) atomicAdd(rS + 4 * wv + (lane >> 4), t1);
      }
      // prefetch partial(t+1) = bc + Wx*x(t+1) + Wo*out(t)  (VMEM, overlaps barrier)
      if (tid < CO) {
        const int tt = (t + 1 < T_STEPS) ? t + 1 : T_STEPS - 1;
        float acc = bcv[tid];
        const float* xr = inp + ((size_t)tt * BATCH + b) * 64;
        const float* wc = Wc + tid;
#pragma unroll 8
        for (int i = 0; i < 64; ++i) acc = fmaf(xr[i], wc[(size_t)i * CO], acc);
        const float* wc2 = Wc + (size_t)64 * CO + tid;
#pragma unroll 8
        for (int i = 0; i < 64; ++i) acc = fmaf(outP[i], wc2[(size_t)i * CO], acc);
        paccT[tid] = acc;
      }
    }
    expct += NBPB; gbar(ctr, expct);   // barrier B

    // ---------- phase 3: normalize weights + publish halos (no mem pass) ----------
    if (tid == 0) { red[2] = 1.f / aload(sS + 2); red[3] = 1.f / aload(sS + 3); }
    __syncthreads();
    if (tid < LSL) {
      float nR = wbR[tid] * red[2];
      float nW = wbW[tid] * red[3];
      wpR[tid] = nR; wpW[tid] = nW;
      if (tid == 0)       { astore(hPn + 0, nR); astore(hPn + 2, nW); }
      if (tid == LSL - 1) { astore(hPn + 1, nR); astore(hPn + 3, nW); }
    }
    __syncthreads();
  }
}

extern "C" void kernel_launch(void* const* d_in, const int* in_sizes, int n_in,
                              void* d_out, int out_size, void* d_ws, size_t ws_size,
                              hipStream_t stream) {
  const float* inp = (const float*)d_in[0];
  const float* Wc  = (const float*)d_in[1];
  const float* bcv = (const float*)d_in[2];
  float* dout = (float*)d_out;
  float* comm = (float*)d_ws;

  hipMemsetAsync(comm, 0, (size_t)COMM_FLOATS * sizeof(float), stream);

  void* args[] = { (void*)&inp, (void*)&Wc, (void*)&bcv, (void*)&dout, (void*)&comm };
  hipLaunchCooperativeKernel((void*)ntm_kernel, dim3(NBLK), dim3(NTHR),
                             args, 0, stream);
}

// Round 9
// 892.444 us; speedup vs baseline: 7.7279x; 1.3257x over previous
//
#include <hip/hip_runtime.h>

#define T_STEPS 32
#define BATCH   16
#define NBPB    8
#define NBLK    (BATCH * NBPB)     // 128
#define NTHR    1024
#define LSL     512                // l-slots per block
#define MSTR    65                 // odd stride: 2 lanes/bank everywhere (free)
#define CO      332

// comm floats (zeroed by hipMemsetAsync)
#define OFF_CTR   0                                        // [16][32] uints
#define OFF_SLS   512                                      // [b][t][g][2] S partials
#define OFF_SLP   (OFF_SLS + BATCH*T_STEPS*16)             // [b][t][g][2] P partials
#define OFF_RSUM  (OFF_SLP + BATCH*T_STEPS*16)             // [b][t][64] r~ sums
#define OFF_HE    (OFF_RSUM + BATCH*T_STEPS*64)            // [b][t][g][4] er halos
#define OFF_HP    (OFF_HE + BATCH*T_STEPS*NBPB*4)          // [b][0..32][g][4] wp halos
#define COMM_FLOATS (OFF_HP + BATCH*(T_STEPS+1)*NBPB*4)

__device__ __forceinline__ float waveSum(float v) {
#pragma unroll
  for (int off = 32; off > 0; off >>= 1) v += __shfl_xor(v, off, 64);
  return v;
}
__device__ __forceinline__ float sigmoidf(float x) { return 1.f / (1.f + __expf(-x)); }
__device__ __forceinline__ float softplusf(float x) { return x > 15.f ? x : log1pf(__expf(x)); }
__device__ __forceinline__ float aload(const float* p) {
  return __hip_atomic_load(p, __ATOMIC_RELAXED, __HIP_MEMORY_SCOPE_AGENT);
}
__device__ __forceinline__ void astore(float* p, float v) {
  __hip_atomic_store(p, v, __ATOMIC_RELAXED, __HIP_MEMORY_SCOPE_AGENT);
}

// 8-block per-batch barrier; gbar's __syncthreads drains vmcnt so all prior
// stores/atomics are L2-visible before the counter bump.
__device__ __forceinline__ void gbar(unsigned* c, unsigned expected) {
  __syncthreads();
  if (threadIdx.x == 0) {
    atomicAdd(c, 1u);
    while (__hip_atomic_load(c, __ATOMIC_RELAXED, __HIP_MEMORY_SCOPE_AGENT) < expected)
      __builtin_amdgcn_s_sleep(1);
  }
  __syncthreads();
}

__global__ void __launch_bounds__(NTHR, 1) ntm_kernel(
    const float* __restrict__ inp, const float* __restrict__ Wc,
    const float* __restrict__ bcv, float* __restrict__ dout,
    float* __restrict__ comm)
{
  const int blkid = blockIdx.x;
  const int b   = blkid & 15;     // blkid%8 == b%8 -> per-batch XCD co-location
  const int g   = blkid >> 4;
  const int tid = threadIdx.x;
  const int wv  = tid >> 6;
  const int lane = tid & 63;

  __shared__ float mem[LSL * MSTR];                 // 130 KB block-private
  __shared__ float wpR[LSL], wpW[LSL];              // normalized prev weights
  __shared__ float wbR[LSL], wbW[LSL];              // sharpened, unnormalized
  __shared__ float erR[LSL], erW[LSL];              // softmax numerators
  __shared__ float kr[64], kw[64], psc[12];
  __shared__ float eldsA[2][64], aldsA[2][64];      // e/a double buffer
  __shared__ float paccT[CO], outP[64];
  __shared__ float scrA[16], scrB[16], red[8];

  unsigned* ctr = (unsigned*)comm + b * 32;

  // ---------------- prologue ----------------
  for (int i = tid; i < LSL * MSTR; i += NTHR) mem[i] = 0.f;
  if (tid < LSL) { wpR[tid] = 0.f; wpW[tid] = 0.f; }
  if (g == 0 && tid == 0) { wpR[0] = 1.f; wpW[0] = 1.f; }
  if (tid < 64) outP[tid] = 0.f;
  if (tid < CO) {            // pacc(0) = bc + Wx*x(0); out(-1)=0, r(-1)=0
    float acc = bcv[tid];
    const float* x0 = inp + b * 64;
    const float* wc = Wc + tid;
#pragma unroll 8
    for (int i = 0; i < 64; ++i) acc = fmaf(x0[i], wc[(size_t)i * CO], acc);
    paccT[tid] = acc;
  }
  {
    float* hp0 = comm + OFF_HP + ((size_t)(b * (T_STEPS + 1)) * NBPB + g) * 4;
    if (tid == 0) { float v = (g == 0) ? 1.f : 0.f; astore(hp0 + 0, v); astore(hp0 + 2, v); }
    if (tid == 1) { astore(hp0 + 1, 0.f); astore(hp0 + 3, 0.f); }
  }
  unsigned expct = NBPB;
  gbar(ctr, expct);

  float invPRprev = 0.f;

  for (int t = 0; t < T_STEPS; ++t) {
    float* slS = comm + OFF_SLS + (size_t)(b * T_STEPS + t) * 16;
    float* slP = comm + OFF_SLP + (size_t)(b * T_STEPS + t) * 16;
    float* rS  = comm + OFF_RSUM + (size_t)(b * T_STEPS + t) * 64;
    float* hE  = comm + OFF_HE + ((size_t)(b * T_STEPS + t) * NBPB + g) * 4;
    float* hPn = comm + OFF_HP + ((size_t)(b * (T_STEPS + 1) + t + 1) * NBPB + g) * 4;

    // ---------- phase 0: GEMM(t) = paccT + Wr*r(t-1) ----------
    if (tid < 2 * CO) {
      const int col = tid >> 1, h = tid & 1;
      float part = h ? 0.f : paccT[col];
      if (t > 0) {
        const float* rSp = comm + OFF_RSUM + (size_t)(b * T_STEPS + t - 1) * 64;
        const float* wc = Wc + (size_t)(128 + 32 * h) * CO + col;
        float racc = 0.f;
#pragma unroll 8
        for (int j = 0; j < 32; ++j)
          racc = fmaf(aload(rSp + 32 * h + j), wc[(size_t)j * CO], racc);
        part = fmaf(racc, invPRprev, part);
      }
      float acc = part + __shfl_xor(part, 1, 64);
      if (h == 0) {
        if (col < 64) { outP[col] = acc; if (g == 0) dout[((size_t)t * BATCH + b) * 64 + col] = acc; }
        else if (col < 128) kr[col - 64] = acc;
        else if (col < 134) psc[col - 128] = acc;          // beta_r,g_r,ga_r,s_r0..2
        else if (col < 198) kw[col - 134] = acc;
        else if (col < 204) psc[6 + col - 198] = acc;      // beta_w,g_w,ga_w,s_w0..2
        else if (col < 268) eldsA[t & 1][col - 204] = sigmoidf(acc);
        else                aldsA[t & 1][col - 268] = acc;
      }
    }
    __syncthreads();
    if (wv == 0)      { float v = kr[lane]; float s = waveSum(v * v); if (!lane) red[4] = 1.f / sqrtf(s + 1e-14f); }
    else if (wv == 1) { float v = kw[lane]; float s = waveSum(v * v); if (!lane) red[5] = 1.f / sqrtf(s + 1e-14f); }
    else if (wv == 2 && !lane) { red[6] = softplusf(psc[0]); red[7] = softplusf(psc[6]); }
    __syncthreads();

    // ---------- phase 1: fused lazy-update(t-1) + content addressing ----------
    {
      const float invnkR = red[4], invnkW = red[5];
      const float betaR = red[6], betaW = red[7];
      const int l = tid >> 1, h = tid & 1;
      float* mrow = &mem[l * MSTR + 32 * h];
      const float* eh = &eldsA[(t + 1) & 1][32 * h];   // e(t-1)
      const float* ah = &aldsA[(t + 1) & 1][32 * h];
      const float* krh = kr + 32 * h;
      const float* kwh = kw + 32 * h;
      float ss = 0.f, dr = 0.f, dw = 0.f;
      if (t > 0) {
        const float wWl = wpW[l];
#pragma unroll 8
        for (int i = 0; i < 32; ++i) {
          float v = mrow[i];
          v = fmaf(wWl, ah[i], fmaf(v, -(wWl * eh[i]), v));
          mrow[i] = v;
          ss = fmaf(v, v, ss); dr = fmaf(v, krh[i], dr); dw = fmaf(v, kwh[i], dw);
        }
      }
      ss += __shfl_xor(ss, 1, 64);
      dr += __shfl_xor(dr, 1, 64);
      dw += __shfl_xor(dw, 1, 64);
      float rinv = rsqrtf(ss + 1e-14f);
      float eRv = __expf(betaR * (dr * rinv * invnkR - 1.f));   // stable: K<=1
      float eWv = __expf(betaW * (dw * rinv * invnkW - 1.f));
      if (h == 0) {
        erR[l] = eRv; erW[l] = eWv;
        if (l == 0)       { astore(hE + 0, eRv); astore(hE + 2, eWv); }
        if (l == LSL - 1) { astore(hE + 1, eRv); astore(hE + 3, eWv); }
      }
      float sRl = h ? 0.f : eRv, sWl = h ? 0.f : eWv;
      sRl = waveSum(sRl); sWl = waveSum(sWl);
      if (!lane) { scrA[wv] = sRl; scrB[wv] = sWl; }
    }
    __syncthreads();
    if (tid == 0) {
      float a = 0.f, bb = 0.f;
      for (int j = 0; j < 16; ++j) { a += scrA[j]; bb += scrB[j]; }
      astore(slS + 2 * g + 0, a); astore(slS + 2 * g + 1, bb);
    }
    expct += NBPB; gbar(ctr, expct);   // barrier A

    // ---------- phase 2: sharpen (waves 0-7) || prefetch GEMM (waves 8+) ----------
    if (tid < LSL) {
      float sR = 0.f, sW = 0.f;
#pragma unroll
      for (int j = 0; j < 8; ++j) { sR += aload(slS + 2 * j); sW += aload(slS + 2 * j + 1); }
      const float invSR = 1.f / sR, invSW = 1.f / sW;
      float gR = sigmoidf(psc[1]), gaR = softplusf(psc[2]) + 1.f;
      float x0 = psc[3], x1 = psc[4], x2 = psc[5];
      float mx = fmaxf(x0, fmaxf(x1, x2));
      float e0 = __expf(x0 - mx), e1 = __expf(x1 - mx), e2 = __expf(x2 - mx);
      float es = 1.f / (e0 + e1 + e2);
      float sr0 = e0 * es, sr1 = e1 * es, sr2 = e2 * es;
      float gW = sigmoidf(psc[7]), gaW = softplusf(psc[8]) + 1.f;
      float y0 = psc[9], y1 = psc[10], y2 = psc[11];
      float my = fmaxf(y0, fmaxf(y1, y2));
      float f0 = __expf(y0 - my), f1 = __expf(y1 - my), f2 = __expf(y2 - my);
      float fs = 1.f / (f0 + f1 + f2);
      float sw0 = f0 * fs, sw1 = f1 * fs, sw2 = f2 * fs;
      const float aR = gR * invSR, bR = 1.f - gR;
      const float aW = gW * invSW, bW = 1.f - gW;

      float erm, ewm, prm, pwm, erp, ewp, prp, pwp;
      if (tid == 0) {
        const int gm = (g + 7) & 7;
        const float* hEm = comm + OFF_HE + ((size_t)(b * T_STEPS + t) * NBPB + gm) * 4;
        const float* hPm = comm + OFF_HP + ((size_t)(b * (T_STEPS + 1) + t) * NBPB + gm) * 4;
        erm = aload(hEm + 1); ewm = aload(hEm + 3);
        prm = aload(hPm + 1); pwm = aload(hPm + 3);
      } else { erm = erR[tid - 1]; ewm = erW[tid - 1]; prm = wpR[tid - 1]; pwm = wpW[tid - 1]; }
      if (tid == LSL - 1) {
        const int gp = (g + 1) & 7;
        const float* hEp = comm + OFF_HE + ((size_t)(b * T_STEPS + t) * NBPB + gp) * 4;
        const float* hPp = comm + OFF_HP + ((size_t)(b * (T_STEPS + 1) + t) * NBPB + gp) * 4;
        erp = aload(hEp + 0); ewp = aload(hEp + 2);
        prp = aload(hPp + 0); pwp = aload(hPp + 2);
      } else { erp = erR[tid + 1]; ewp = erW[tid + 1]; prp = wpR[tid + 1]; pwp = wpW[tid + 1]; }

      float wgm = aR * erm + bR * prm;
      float wg0 = aR * erR[tid] + bR * wpR[tid];
      float wgp = aR * erp + bR * prp;
      float wR = __powf(sr0 * wgm + sr1 * wg0 + sr2 * wgp, gaR);
      float vgm = aW * ewm + bW * pwm;
      float vg0 = aW * erW[tid] + bW * wpW[tid];
      float vgp = aW * ewp + bW * pwp;
      float wW = __powf(sw0 * vgm + sw1 * vg0 + sw2 * vgp, gaW);
      wbR[tid] = wR; wbW[tid] = wW;
      float pRl = waveSum(wR), pWl = waveSum(wW);
      if (!lane) { scrA[wv] = pRl; scrB[wv] = pWl; }
    } else if (tid < LSL + CO) {
      // prefetch pacc(t+1) = bc + Wx*x(t+1) + Wo*out(t): overlaps sharpen
      const int col = tid - LSL;
      const int tt = (t + 1 < T_STEPS) ? t + 1 : T_STEPS - 1;
      float acc = bcv[col];
      const float* xr = inp + ((size_t)tt * BATCH + b) * 64;
      const float* wc = Wc + col;
#pragma unroll 8
      for (int i = 0; i < 64; ++i) acc = fmaf(xr[i], wc[(size_t)i * CO], acc);
      const float* wc2 = Wc + (size_t)64 * CO + col;
#pragma unroll 8
      for (int i = 0; i < 64; ++i) acc = fmaf(outP[i], wc2[(size_t)i * CO], acc);
      paccT[col] = acc;
    }
    __syncthreads();
    if (tid == 0) {
      float a = 0.f, bb = 0.f;
      for (int j = 0; j < 8; ++j) { a += scrA[j]; bb += scrB[j]; }
      astore(slP + 2 * g + 0, a); astore(slP + 2 * g + 1, bb);
    }
    // r~ partials over post-update mem (wave wv owns rows w=4wv..4wv+3)
    {
      float wbv[8];
#pragma unroll
      for (int k = 0; k < 8; ++k) wbv[k] = wbR[lane + 64 * k];
      float racc4[4];
#pragma unroll
      for (int r = 0; r < 4; ++r) {
        const int w = 4 * wv + r;
        float acc = 0.f;
#pragma unroll
        for (int k = 0; k < 8; ++k)
          acc = fmaf(mem[(lane + 64 * k) * MSTR + w], wbv[k], acc);
        racc4[r] = acc;
      }
      const bool u5 = (lane & 32) != 0;
      float t2[2];
#pragma unroll
      for (int j = 0; j < 2; ++j) {
        float sent = u5 ? racc4[j] : racc4[j + 2];
        float keep = u5 ? racc4[j + 2] : racc4[j];
        t2[j] = keep + __shfl_xor(sent, 32, 64);
      }
      const bool u4 = (lane & 16) != 0;
      float sent = u4 ? t2[0] : t2[1];
      float keep = u4 ? t2[1] : t2[0];
      float t1 = keep + __shfl_xor(sent, 16, 64);
      t1 += __shfl_xor(t1, 8, 64);
      t1 += __shfl_xor(t1, 4, 64);
      t1 += __shfl_xor(t1, 2, 64);
      t1 += __shfl_xor(t1, 1, 64);
      if ((lane & 15) == 0) atomicAdd(rS + 4 * wv + (lane >> 4), t1);
    }
    expct += NBPB; gbar(ctr, expct);   // barrier B

    // ---------- phase 3: normalize weights + publish halos ----------
    if (tid < 2 * CO) {
      float pR = 0.f, pW = 0.f;
#pragma unroll
      for (int j = 0; j < 8; ++j) { pR += aload(slP + 2 * j); pW += aload(slP + 2 * j + 1); }
      const float invPR = 1.f / pR, invPW = 1.f / pW;
      invPRprev = invPR;
      if (tid < LSL) {
        float nR = wbR[tid] * invPR, nW = wbW[tid] * invPW;
        wpR[tid] = nR; wpW[tid] = nW;
        if (tid == 0)       { astore(hPn + 0, nR); astore(hPn + 2, nW); }
        if (tid == LSL - 1) { astore(hPn + 1, nR); astore(hPn + 3, nW); }
      }
    }
    __syncthreads();
  }
}

extern "C" void kernel_launch(void* const* d_in, const int* in_sizes, int n_in,
                              void* d_out, int out_size, void* d_ws, size_t ws_size,
                              hipStream_t stream) {
  const float* inp = (const float*)d_in[0];
  const float* Wc  = (const float*)d_in[1];
  const float* bcv = (const float*)d_in[2];
  float* dout = (float*)d_out;
  float* comm = (float*)d_ws;

  hipMemsetAsync(comm, 0, (size_t)COMM_FLOATS * sizeof(float), stream);

  void* args[] = { (void*)&inp, (void*)&Wc, (void*)&bcv, (void*)&dout, (void*)&comm };
  hipLaunchCooperativeKernel((void*)ntm_kernel, dim3(NBLK), dim3(NTHR),
                             args, 0, stream);
}